// Round 10
// baseline (156.813 us; speedup 1.0000x reference)
//
#include <hip/hip_runtime.h>
#include <hip/hip_bf16.h>
#include <math.h>

#define BATCH 2
#define CH 512
#define SEQ 4096
#define KDIM 256
#define VDIM 512
#define NHEADS 8
#define DK 32
#define DV 64

typedef unsigned short u16;
typedef unsigned int u32;
typedef __attribute__((ext_vector_type(8))) short bf16x8;
typedef __attribute__((ext_vector_type(4))) float f32x4;

__device__ __forceinline__ u16 f2bf(float f) {          // RNE
    u32 x = __float_as_uint(f);
    u32 r = (x + 0x7fffu + ((x >> 16) & 1u)) >> 16;
    return (u16)r;
}
__device__ __forceinline__ u16 f2bf_fast(float f) {     // half-up
    return (u16)((__float_as_uint(f) + 0x8000u) >> 16);
}
__device__ __forceinline__ u32 pack2f(float lo, float hi) {
    return (u32)f2bf_fast(lo) | (((__float_as_uint(hi) + 0x8000u) >> 16) << 16);
}
// v_cvt_pk_bf16_f32: D = {bf16(lo), bf16(hi)} (lo in low 16 bits), RNE.
__device__ __forceinline__ u32 cvtpk_bf16(float lo, float hi) {
    u32 r;
    asm("v_cvt_pk_bf16_f32 %0, %1, %2" : "=v"(r) : "v"(lo), "v"(hi));
    return r;
}

#define QSCALE (0.17677669529663687f * 1.4426950408889634f)  // 1/sqrt(dk)*log2e

// ===========================================================================
// FAST PATH
// ===========================================================================

// prep v2 (round-9 validated): WEIGHTS ONLY.
// 192 blocks: bid<128 -> Wall (Wq|Wk|Wv, Q pre-scaled), else -> WoT.
__global__ __launch_bounds__(256) void prep(
    const float* __restrict__ Wq, const float* __restrict__ Wk,
    const float* __restrict__ Wv, const float* __restrict__ Wo,
    u16* __restrict__ Wall, u16* __restrict__ WoT)
{
    __shared__ u16 T[64 * 72];
    const int bid = blockIdx.x;
    const int t = threadIdx.x;
    const int tr = t >> 4;
    const int tc4 = (t & 15) * 4;

    const float* src; u16* dst;
    int src_row0, src_col0, src_pitch, dst_row0, dst_col0, dst_pitch;
    float scale = 1.0f;

    if (bid < 128) {
        const int nt = bid >> 3, ct = bid & 7;
        if (nt < 4)      { src = Wq; src_col0 = nt * 64;       src_pitch = KDIM; scale = QSCALE; }
        else if (nt < 8) { src = Wk; src_col0 = (nt - 4) * 64; src_pitch = KDIM; }
        else             { src = Wv; src_col0 = (nt - 8) * 64; src_pitch = VDIM; }
        src_row0 = ct * 64;
        dst = Wall; dst_row0 = nt * 64; dst_col0 = ct * 64; dst_pitch = 512;
    } else {
        const int r = bid - 128;
        const int kt = r >> 3, nt = r & 7;
        src = Wo; src_row0 = kt * 64; src_col0 = nt * 64; src_pitch = 512;
        dst = WoT; dst_row0 = nt * 64; dst_col0 = kt * 64; dst_pitch = 512;
    }

#pragma unroll
    for (int j = 0; j < 4; ++j) {
        const int row = j * 16 + tr;
        const float4 v = *reinterpret_cast<const float4*>(
            &src[(size_t)(src_row0 + row) * src_pitch + src_col0 + tc4]);
        T[(tc4 + 0) * 72 + row] = f2bf(v.x * scale);
        T[(tc4 + 1) * 72 + row] = f2bf(v.y * scale);
        T[(tc4 + 2) * 72 + row] = f2bf(v.z * scale);
        T[(tc4 + 3) * 72 + row] = f2bf(v.w * scale);
    }
    __syncthreads();
#pragma unroll
    for (int j = 0; j < 4; ++j) {
        const int orow = j * 16 + tr;
        const ushort4 o = *reinterpret_cast<ushort4*>(&T[orow * 72 + tc4]);
        *reinterpret_cast<ushort4*>(
            &dst[(size_t)(dst_row0 + orow) * dst_pitch + dst_col0 + tc4]) = o;
    }
}

// ---------------------------------------------------------------------------
// qkvX v3 (this round's ONE change): 128x64-tile GEMM (was 128x128).
// Rationale: qkvX was grid-limited at 512 blocks = 2 blocks/CU; the LDS
// footprint admits 4-5. m132's data (3->2 blocks/CU cost 874->508 TF on the
// same structure) says blocks/CU is the dominant dial in this stall-bound
// regime. BN=64 doubles the grid to 1024 blocks = 4 blocks/CU (LDS 30KB).
// Geometry is EXACTLY oproj3-v2's validated form (B staging, fragments,
// epilogue) with round-9's validated A-from-X transpose-on-stage unchanged.
// ---------------------------------------------------------------------------
#define ASW(row, colu16) ((row) * 40 + ((colu16) ^ ((((row) >> 2) & 3) << 3)))

__global__ __launch_bounds__(256, 2) void qkvX(
    const float* __restrict__ X, const u16* __restrict__ Wall,
    u16* __restrict__ Qh, u16* __restrict__ Kh, u16* __restrict__ Vh)
{
    __shared__ __align__(16) u16 As[2][128 * 40];
    __shared__ __align__(16) u16 Bs[2][64 * 40];
    const int tid = threadIdx.x;
    const int wv = tid >> 6, lane = tid & 63;
    const int c = lane & 15, quad = lane >> 4;
    const int wm = wv & 1, wn = wv >> 1;          // 2x2 waves over 128x64
    const int m0 = blockIdx.x * 128;
    const int ny = blockIdx.y;                    // 0..15 over concat N=1024
    const int n0 = ny * 64;

    u16* Y; int N, nbase;
    if (ny < 4)      { Y = Qh; N = KDIM; nbase = 0; }
    else if (ny < 8) { Y = Kh; N = KDIM; nbase = 256; }
    else             { Y = Vh; N = VDIM; nbase = 512; }

    // A staging (round-9 validated): thread -> channels {2cp,2cp+1},
    // s-rows {s4..s4+3, 64+s4..64+s4+3}
    const int cp = tid >> 4;          // 0..15
    const int s4 = (tid & 15) * 4;    // 0..60
    const int bb = m0 >> 12;          // batch (tile never straddles)
    const float* Xb = X + (size_t)bb * CH * SEQ + (m0 & 4095);

    // B staging (oproj3-v2 validated): 1 uint4/thread, 64 rows x 32 cols
    const int srB = tid >> 2, scB = (tid & 3) * 8;

    f32x4 acc[4][2];
#pragma unroll
    for (int j = 0; j < 4; ++j)
#pragma unroll
        for (int g = 0; g < 2; ++g) acc[j][g] = (f32x4){0.f, 0.f, 0.f, 0.f};

    float4 xa0, xb0, xa1, xb1;
    uint4 br0;
    auto ld = [&](int k0) {
        const size_t ch0 = (size_t)(k0 + 2 * cp) * SEQ;
        const size_t ch1 = (size_t)(k0 + 2 * cp + 1) * SEQ;
        xa0 = *reinterpret_cast<const float4*>(&Xb[ch0 + s4]);
        xb0 = *reinterpret_cast<const float4*>(&Xb[ch1 + s4]);
        xa1 = *reinterpret_cast<const float4*>(&Xb[ch0 + 64 + s4]);
        xb1 = *reinterpret_cast<const float4*>(&Xb[ch1 + 64 + s4]);
        br0 = *reinterpret_cast<const uint4*>(
            &Wall[(size_t)(n0 + srB) * 512 + k0 + scB]);
    };
    auto stage = [&](int buf) {
        const float a0[4] = {xa0.x, xa0.y, xa0.z, xa0.w};
        const float b0[4] = {xb0.x, xb0.y, xb0.z, xb0.w};
        const float a1[4] = {xa1.x, xa1.y, xa1.z, xa1.w};
        const float b1[4] = {xb1.x, xb1.y, xb1.z, xb1.w};
#pragma unroll
        for (int i = 0; i < 4; ++i) {
            *reinterpret_cast<u32*>(&As[buf][ASW(s4 + i, 2 * cp)]) =
                pack2f(a0[i], b0[i]);
            *reinterpret_cast<u32*>(&As[buf][ASW(64 + s4 + i, 2 * cp)]) =
                pack2f(a1[i], b1[i]);
        }
        *reinterpret_cast<uint4*>(&Bs[buf][srB * 40 + scB]) = br0;
    };

    ld(0);
    stage(0);
    ld(32);

    for (int i = 0; i < 16; ++i) {
        const int cur = i & 1;
        __syncthreads();
        stage(cur ^ 1);
        const int k0n = (i + 2 < 16) ? (i + 2) * 32 : 15 * 32;
        ld(k0n);
        bf16x8 af[4], bf_[2];
#pragma unroll
        for (int j = 0; j < 4; ++j)
            af[j] = *reinterpret_cast<bf16x8*>(
                &As[cur][ASW(wm * 64 + 16 * j + c, quad * 8)]);
#pragma unroll
        for (int g = 0; g < 2; ++g)
            bf_[g] = *reinterpret_cast<bf16x8*>(
                &Bs[cur][(wn * 32 + 16 * g + c) * 40 + quad * 8]);
#pragma unroll
        for (int j = 0; j < 4; ++j)
#pragma unroll
            for (int g = 0; g < 2; ++g)
                acc[j][g] = __builtin_amdgcn_mfma_f32_16x16x32_bf16(
                    af[j], bf_[g], acc[j][g], 0, 0, 0);
    }
#pragma unroll
    for (int j = 0; j < 4; ++j)
#pragma unroll
        for (int r = 0; r < 4; ++r) {
            const int row = m0 + wm * 64 + 16 * j + quad * 4 + r;
            const int col = n0 - nbase + wn * 32 + c;
#pragma unroll
            for (int g = 0; g < 2; ++g)
                Y[(size_t)row * N + col + 16 * g] = f2bf(acc[j][g][r]);
        }
}

// ---------------------------------------------------------------------------
// oproj3 v2 (round-7/9 validated): 128x64-tile GEMM, grid (64,8) = 512 blocks.
// ---------------------------------------------------------------------------
__global__ __launch_bounds__(256, 2) void oproj3(
    const u16* __restrict__ A, const u16* __restrict__ WoT,
    float* __restrict__ Out)
{
    __shared__ __align__(16) u16 As[2][128 * 40];
    __shared__ __align__(16) u16 Bs[2][64 * 40];
    const int tid = threadIdx.x;
    const int wv = tid >> 6, lane = tid & 63;
    const int c = lane & 15, quad = lane >> 4;
    const int wm = wv & 1, wn = wv >> 1;
    const int m0 = blockIdx.x * 128;
    const int n0 = blockIdx.y * 64;

    const int srow = tid >> 1, scol = (tid & 1) * 16;   // A staging
    const int srB = tid >> 2, scB = (tid & 3) * 8;      // B staging (1 uint4/thread)

    f32x4 acc[4][2];
#pragma unroll
    for (int j = 0; j < 4; ++j)
#pragma unroll
        for (int g = 0; g < 2; ++g) acc[j][g] = (f32x4){0.f, 0.f, 0.f, 0.f};

    uint4 ar0, ar1, br0;
    auto ld = [&](int k0) {
        const uint4* ap = reinterpret_cast<const uint4*>(
            &A[(size_t)(m0 + srow) * 512 + k0 + scol]);
        ar0 = ap[0]; ar1 = ap[1];
        br0 = *reinterpret_cast<const uint4*>(
            &WoT[(size_t)(n0 + srB) * 512 + k0 + scB]);
    };
    auto stage = [&](int buf) {
        uint4* ad = reinterpret_cast<uint4*>(&As[buf][srow * 40 + scol]);
        ad[0] = ar0; ad[1] = ar1;
        *reinterpret_cast<uint4*>(&Bs[buf][srB * 40 + scB]) = br0;
    };

    ld(0);
    stage(0);
    ld(32);

    for (int i = 0; i < 16; ++i) {
        const int cur = i & 1;
        __syncthreads();
        stage(cur ^ 1);
        const int k0n = (i + 2 < 16) ? (i + 2) * 32 : 15 * 32;
        ld(k0n);
        bf16x8 af[4], bf_[2];
#pragma unroll
        for (int j = 0; j < 4; ++j)
            af[j] = *reinterpret_cast<bf16x8*>(
                &As[cur][(wm * 64 + 16 * j + c) * 40 + quad * 8]);
#pragma unroll
        for (int g = 0; g < 2; ++g)
            bf_[g] = *reinterpret_cast<bf16x8*>(
                &Bs[cur][(wn * 32 + 16 * g + c) * 40 + quad * 8]);
#pragma unroll
        for (int j = 0; j < 4; ++j)
#pragma unroll
            for (int g = 0; g < 2; ++g)
                acc[j][g] = __builtin_amdgcn_mfma_f32_16x16x32_bf16(
                    af[j], bf_[g], acc[j][g], 0, 0, 0);
    }
#pragma unroll
    for (int j = 0; j < 4; ++j)
#pragma unroll
        for (int r = 0; r < 4; ++r) {
            const int row = m0 + wm * 64 + 16 * j + quad * 4 + r;
            const int col = n0 + wn * 32 + c;
#pragma unroll
            for (int g = 0; g < 2; ++g)
                Out[(size_t)row * 512 + col + 16 * g] = acc[j][g][r];
        }
}

// ===========================================================================
// flash v15 (round-5/7/9 validated text, UNCHANGED): paired A/B q-blocks,
// T12 in-register P transform, XOR-swizzled unpadded K/V tiles. ~57us,
// absmax 0.015625. Un-paired variant failed correctness twice — do not
// re-attempt without a device-side debugging path.
// ===========================================================================
#define KSW(row, col) ((row) * 32 + ((col) ^ (((row) & 3) << 3)))
#define VSW(row, col) ((row) * 64 + ((col) ^ (((row) & 7) << 3)))

__global__ __launch_bounds__(512, 4) void flash_mfma(
    const u16* __restrict__ Q, const u16* __restrict__ K,
    const u16* __restrict__ V, u16* __restrict__ AO)
{
    __shared__ __align__(16) union {
        struct {
            u16 Kl[2][2][64 * 32];
            u16 Vt[2][2][64 * 64];
        } t;
        float mg[4][64][40];
    } sh;

    const int tid  = threadIdx.x;
    const int w    = tid >> 6;
    const int ws   = w & 3;
    const int wg   = w >> 2;
    const int lane = tid & 63;
    const int c    = lane & 15;
    const int quad = lane >> 4;
    const int h = blockIdx.y, b = blockIdx.z;

    const int qbA = blockIdx.x;
    const int qbB = 63 - qbA;
    const int q0A = qbA * 64, q0B = qbB * 64;

    const u16* Qb = Q + (size_t)b * SEQ * KDIM + h * DK;
    const u16* Kb = K + (size_t)b * SEQ * KDIM + h * DK;
    const u16* Vb = V + (size_t)b * SEQ * VDIM + h * DV;
    u16* AOb = AO + (size_t)b * SEQ * VDIM + h * DV;

    const bf16x8 qfA = *reinterpret_cast<const bf16x8*>(
        &Qb[(size_t)(q0A + ws * 16 + c) * KDIM + quad * 8]);
    const bf16x8 qfB = *reinterpret_cast<const bf16x8*>(
        &Qb[(size_t)(q0B + ws * 16 + c) * KDIM + quad * 8]);

    // constant all-ones A-frag: bf16 1.0 = 0x3F80 in every element
    const bf16x8 ones = {(short)0x3F80, (short)0x3F80, (short)0x3F80, (short)0x3F80,
                         (short)0x3F80, (short)0x3F80, (short)0x3F80, (short)0x3F80};

    f32x4 oA[4], oB[4];
#pragma unroll
    for (int g = 0; g < 4; ++g) {
        oA[g] = (f32x4){0.f, 0.f, 0.f, 0.f};
        oB[g] = (f32x4){0.f, 0.f, 0.f, 0.f};
    }
    f32x4 laccA = {0.f, 0.f, 0.f, 0.f}, laccB = {0.f, 0.f, 0.f, 0.f};

    const int t256 = tid & 255;
    const int krow = t256 >> 2, kc8 = (t256 & 3) * 8;
    const int vs0 = (t256 & 31) * 2, vd0 = (t256 >> 5) * 8;

    const int qrbase = ws * 16 + c;   // per-lane q row (within q-block)
    const int T = (qbB >> 1) + 1;

    uint4 kreg, vra, vrb;
    auto ldtile = [&](int kb) {
        const int k0 = kb * 64;
        kreg = *reinterpret_cast<const uint4*>(&Kb[(size_t)(k0 + krow) * KDIM + kc8]);
        vra  = *reinterpret_cast<const uint4*>(&Vb[(size_t)(k0 + vs0) * VDIM + vd0]);
        vrb  = *reinterpret_cast<const uint4*>(&Vb[(size_t)(k0 + vs0 + 1) * VDIM + vd0]);
    };
    auto stagetile = [&](int buf) {
        *reinterpret_cast<uint4*>(&sh.t.Kl[wg][buf][KSW(krow, kc8)]) = kreg;
        union { uint4 q; u16 s[8]; } ra, rb;
        ra.q = vra; rb.q = vrb;
#pragma unroll
        for (int i = 0; i < 8; ++i) {
            u32 packed = (u32)ra.s[i] | ((u32)rb.s[i] << 16);
            *reinterpret_cast<u32*>(&sh.t.Vt[wg][buf][VSW(vd0 + i, vs0)]) = packed;
        }
    };

    ldtile(wg);
    stagetile(0);
    ldtile(2 + wg);

    for (int it = 0; it < T; ++it) {
        const int kb = 2 * it + wg;
        const int k0 = kb * 64;
        const int cur = it & 1;
        __syncthreads();
        stagetile(cur ^ 1);
        {
            int kbn = 2 * (it + 2) + wg; if (kbn > 63) kbn = 63;
            ldtile(kbn);
        }
        const u16* Klc = sh.t.Kl[wg][cur];
        const u16* Vtc = sh.t.Vt[wg][cur];

        auto compute = [&](const bf16x8& qf, int q0, bool diag,
                           f32x4* o, f32x4& lacc) {
            // swapped QK^T: lane(c,quad) gets S[q=c][k=16g+quad*4+r]
            f32x4 s[4];
#pragma unroll
            for (int g = 0; g < 4; ++g) {
                const bf16x8 kf = *reinterpret_cast<const bf16x8*>(
                    &Klc[KSW(c + 16 * g, quad * 8)]);
                const f32x4 z = {0.f, 0.f, 0.f, 0.f};
                s[g] = __builtin_amdgcn_mfma_f32_16x16x32_bf16(kf, qf, z, 0, 0, 0);
            }
            if (diag) {
                const int qr = q0 + qrbase;
#pragma unroll
                for (int g = 0; g < 4; ++g) {
                    const int kc0 = k0 + 16 * g + quad * 4;
#pragma unroll
                    for (int r = 0; r < 4; ++r)
                        if (kc0 + r > qr) s[g][r] = -1e30f;
                }
            }
            // exp2 + pack: wk[g][j2] covers k = quad*4 + 16g + 2*j2 + {0,1}
            u32 wk[4][2];
#pragma unroll
            for (int g = 0; g < 4; ++g)
#pragma unroll
                for (int j2 = 0; j2 < 2; ++j2)
                    wk[g][j2] = cvtpk_bf16(
                        __builtin_amdgcn_exp2f(s[g][2 * j2]),
                        __builtin_amdgcn_exp2f(s[g][2 * j2 + 1]));
            // permutation network -> PV B-frags pb0 (k 0..31), pb1 (k 32..63)
            union { u32 wq[4]; bf16x8 v; } ub0, ub1;
#pragma unroll
            for (int j2 = 0; j2 < 2; ++j2) {
                {
                    auto t1 = __builtin_amdgcn_permlane32_swap(
                        wk[0][j2], wk[1][j2], false, false);
                    auto t2 = __builtin_amdgcn_permlane16_swap(
                        (u32)t1[0], (u32)t1[1], false, false);
                    ub0.wq[j2]     = (u32)t2[0];
                    ub0.wq[2 + j2] = (u32)t2[1];
                }
                {
                    auto t1 = __builtin_amdgcn_permlane32_swap(
                        wk[2][j2], wk[3][j2], false, false);
                    auto t2 = __builtin_amdgcn_permlane16_swap(
                        (u32)t1[0], (u32)t1[1], false, false);
                    ub1.wq[j2]     = (u32)t2[0];
                    ub1.wq[2 + j2] = (u32)t2[1];
                }
            }
            const bf16x8 pb0 = ub0.v, pb1 = ub1.v;
            // rowsum via matrix pipe: every reg of lacc holds l[q=c]
            lacc = __builtin_amdgcn_mfma_f32_16x16x32_bf16(ones, pb0, lacc, 0, 0, 0);
            lacc = __builtin_amdgcn_mfma_f32_16x16x32_bf16(ones, pb1, lacc, 0, 0, 0);
            // PV (transposed): o[g] holds O[q=c][dv=16g+quad*4+r]
#pragma unroll
            for (int g = 0; g < 4; ++g) {
                const bf16x8 v0 = *reinterpret_cast<const bf16x8*>(
                    &Vtc[VSW(c + 16 * g, quad * 8)]);
                const bf16x8 v1 = *reinterpret_cast<const bf16x8*>(
                    &Vtc[VSW(c + 16 * g, 32 + quad * 8)]);
                o[g] = __builtin_amdgcn_mfma_f32_16x16x32_bf16(v0, pb0, o[g], 0, 0, 0);
                o[g] = __builtin_amdgcn_mfma_f32_16x16x32_bf16(v1, pb1, o[g], 0, 0, 0);
            }
        };

        if (kb <= qbA) compute(qfA, q0A, kb == qbA, oA, laccA);
        if (kb <= qbB) compute(qfB, q0B, kb == qbB, oB, laccB);
    }

    __syncthreads();
    if (wg == 1) {
        float* m = sh.mg[ws][lane];
#pragma unroll
        for (int g = 0; g < 4; ++g)
#pragma unroll
            for (int r = 0; r < 4; ++r) {
                m[g * 4 + r]      = oA[g][r];
                m[16 + g * 4 + r] = oB[g][r];
            }
        m[32] = laccA[0];
        m[33] = laccB[0];
    }
    __syncthreads();
    if (wg == 0) {
        const float* m = sh.mg[ws][lane];
#pragma unroll
        for (int g = 0; g < 4; ++g)
#pragma unroll
            for (int r = 0; r < 4; ++r) {
                oA[g][r] += m[g * 4 + r];
                oB[g][r] += m[16 + g * 4 + r];
            }
        const float invA = 1.f / (laccA[0] + m[32]);
        const float invB = 1.f / (laccB[0] + m[33]);
        const int rowA = q0A + qrbase;
        const int rowB = q0B + qrbase;
#pragma unroll
        for (int g = 0; g < 4; ++g) {
            ushort4 a4, b4;
            a4.x = f2bf(oA[g][0] * invA); a4.y = f2bf(oA[g][1] * invA);
            a4.z = f2bf(oA[g][2] * invA); a4.w = f2bf(oA[g][3] * invA);
            b4.x = f2bf(oB[g][0] * invB); b4.y = f2bf(oB[g][1] * invB);
            b4.z = f2bf(oB[g][2] * invB); b4.w = f2bf(oB[g][3] * invB);
            *reinterpret_cast<ushort4*>(
                &AOb[(size_t)rowA * VDIM + 16 * g + quad * 4]) = a4;
            *reinterpret_cast<ushort4*>(
                &AOb[(size_t)rowB * VDIM + 16 * g + quad * 4]) = b4;
        }
    }
}

// ===========================================================================
// FALLBACK PATH (ws too small): round-10 projection kernels
// ===========================================================================
__global__ __launch_bounds__(256) void qkv_proj(
    const float* __restrict__ X,
    const float* __restrict__ Wq, const float* __restrict__ Wk,
    const float* __restrict__ Wv,
    u16* __restrict__ Qh, u16* __restrict__ Kh, u16* __restrict__ Vh)
{
    __shared__ __align__(16) u16 Xs[2][64 * 40];
    __shared__ __align__(16) u16 Wsm[2][64 * 40];
    const int tid = threadIdx.x;
    const int w = tid >> 6, lane = tid & 63;
    const int c = lane & 15, quad = lane >> 4;
    const int s0 = blockIdx.x * 64, b = blockIdx.z;
    const int ny = blockIdx.y;

    const float* Wt; u16* Y; int N, n0; float scale;
    if (ny < 4)       { Wt = Wq; Y = Qh; N = KDIM; n0 = ny * 64;       scale = QSCALE; }
    else if (ny < 8)  { Wt = Wk; Y = Kh; N = KDIM; n0 = (ny - 4) * 64; scale = 1.0f; }
    else              { Wt = Wv; Y = Vh; N = VDIM; n0 = (ny - 8) * 64; scale = 1.0f; }

    const float* Xb = X + (size_t)b * CH * SEQ;
    const int cp = tid >> 4;
    const int s4 = (tid & 15) * 4;

    f32x4 acc[4];
#pragma unroll
    for (int g = 0; g < 4; ++g) acc[g] = (f32x4){0.f, 0.f, 0.f, 0.f};

    auto ldx = [&](int c0, float4& a, float4& bb) {
        a  = *reinterpret_cast<const float4*>(&Xb[(size_t)(c0 + 2 * cp) * SEQ + s0 + s4]);
        bb = *reinterpret_cast<const float4*>(&Xb[(size_t)(c0 + 2 * cp + 1) * SEQ + s0 + s4]);
    };
    auto ldwf = [&](int c0, float4& a, float4& bb) {
        a  = *reinterpret_cast<const float4*>(&Wt[(size_t)(c0 + 2 * cp) * N + n0 + s4]);
        bb = *reinterpret_cast<const float4*>(&Wt[(size_t)(c0 + 2 * cp + 1) * N + n0 + s4]);
    };
    auto stage = [&](int buf, const float4& xa, const float4& xb,
                     const float4& wa, const float4& wb) {
        const float a[4] = {xa.x, xa.y, xa.z, xa.w};
        const float bb[4] = {xb.x, xb.y, xb.z, xb.w};
        const float aw[4] = {wa.x, wa.y, wa.z, wa.w};
        const float bw[4] = {wb.x, wb.y, wb.z, wb.w};
#pragma unroll
        for (int i = 0; i < 4; ++i) {
            *reinterpret_cast<u32*>(&Xs[buf][(s4 + i) * 40 + 2 * cp]) = pack2f(a[i], bb[i]);
            *reinterpret_cast<u32*>(&Wsm[buf][(s4 + i) * 40 + 2 * cp]) = pack2f(aw[i], bw[i]);
        }
    };

    float4 xa, xb, wa, wb;
    ldx(0, xa, xb); ldwf(0, wa, wb);
    stage(0, xa, xb, wa, wb);
    ldx(32, xa, xb); ldwf(32, wa, wb);

    for (int i = 0; i < 16; ++i) {
        const int cur = i & 1;
        __syncthreads();
        stage(cur ^ 1, xa, xb, wa, wb);
        const int c0n = (i + 2 < 16) ? (i + 2) * 32 : 15 * 32;
        ldx(c0n, xa, xb); ldwf(c0n, wa, wb);
        const bf16x8 af = *reinterpret_cast<bf16x8*>(&Xs[cur][(w * 16 + c) * 40 + quad * 8]);
#pragma unroll
        for (int g = 0; g < 4; ++g) {
            bf16x8 bf_ = *reinterpret_cast<bf16x8*>(&Wsm[cur][(c + 16 * g) * 40 + quad * 8]);
            acc[g] = __builtin_amdgcn_mfma_f32_16x16x32_bf16(af, bf_, acc[g], 0, 0, 0);
        }
    }
    u16* Yb = Y + (size_t)b * SEQ * N;
#pragma unroll
    for (int r = 0; r < 4; ++r) {
        const int row = s0 + w * 16 + quad * 4 + r;
#pragma unroll
        for (int g = 0; g < 4; ++g)
            Yb[(size_t)row * N + n0 + c + 16 * g] = f2bf(acc[g][r] * scale);
    }
}

__global__ __launch_bounds__(256) void oproj_mfma(
    const u16* __restrict__ A, const float* __restrict__ Wo,
    float* __restrict__ Out)
{
    __shared__ __align__(16) u16 Ws[2][64 * 40];
    const int tid = threadIdx.x;
    const int w = tid >> 6, lane = tid & 63;
    const int c = lane & 15, quad = lane >> 4;
    const int m0 = blockIdx.x * 64, n0 = blockIdx.y * 64;
    const int kp = tid >> 4;
    const int n4 = (tid & 15) * 4;
    const u16* Arow = &A[(size_t)(m0 + w * 16 + c) * 512];

    f32x4 acc[4];
#pragma unroll
    for (int g = 0; g < 4; ++g) acc[g] = (f32x4){0.f, 0.f, 0.f, 0.f};

    auto ldwf = [&](int k0, float4& a, float4& bb) {
        a  = *reinterpret_cast<const float4*>(&Wo[(size_t)(k0 + 2 * kp) * 512 + n0 + n4]);
        bb = *reinterpret_cast<const float4*>(&Wo[(size_t)(k0 + 2 * kp + 1) * 512 + n0 + n4]);
    };
    auto stage = [&](int buf, const float4& wa, const float4& wb) {
        const float a[4] = {wa.x, wa.y, wa.z, wa.w};
        const float bb[4] = {wb.x, wb.y, wb.z, wb.w};
#pragma unroll
        for (int i = 0; i < 4; ++i)
            *reinterpret_cast<u32*>(&Ws[buf][(n4 + i) * 40 + 2 * kp]) = pack2f(a[i], bb[i]);
    };

    float4 wa, wb;
    ldwf(0, wa, wb);
    stage(0, wa, wb);
    ldwf(32, wa, wb);
    bf16x8 afc = *reinterpret_cast<const bf16x8*>(&Arow[quad * 8]);

    for (int i = 0; i < 16; ++i) {
        const int cur = i & 1;
        __syncthreads();
        stage(cur ^ 1, wa, wb);
        const int k0n = (i + 2 < 16) ? (i + 2) * 32 : 15 * 32;
        ldwf(k0n, wa, wb);
        const int k0a = (i + 1 < 16) ? (i + 1) * 32 : 15 * 32;
        const bf16x8 afn = *reinterpret_cast<const bf16x8*>(&Arow[k0a + quad * 8]);
#pragma unroll
        for (int g = 0; g < 4; ++g) {
            bf16x8 bf_ = *reinterpret_cast<bf16x8*>(&Ws[cur][(c + 16 * g) * 40 + quad * 8]);
            acc[g] = __builtin_amdgcn_mfma_f32_16x16x32_bf16(afc, bf_, acc[g], 0, 0, 0);
        }
        afc = afn;
    }
#pragma unroll
    for (int r = 0; r < 4; ++r) {
        const int row = m0 + w * 16 + quad * 4 + r;
#pragma unroll
        for (int g = 0; g < 4; ++g)
            Out[(size_t)row * 512 + n0 + c + 16 * g] = acc[g][r];
    }
}

extern "C" void kernel_launch(void* const* d_in, const int* in_sizes, int n_in,
                              void* d_out, int out_size, void* d_ws, size_t ws_size,
                              hipStream_t stream) {
    const float* X  = (const float*)d_in[0];
    const float* Wq = (const float*)d_in[1];
    const float* Wk = (const float*)d_in[2];
    const float* Wv = (const float*)d_in[3];
    const float* Wo = (const float*)d_in[4];
    float* out = (float*)d_out;

    const size_t qk = (size_t)BATCH * SEQ * KDIM;
    const size_t vs = (size_t)BATCH * SEQ * VDIM;
    u16* Qh  = (u16*)d_ws;        // 4 MB
    u16* Kh  = Qh + qk;           // 4 MB
    u16* Vh  = Kh + qk;           // 8 MB
    u16* XA  = Vh + vs;           // 8 MB: AO after flash (Xb16 slot retired)
    u16* Wall = XA + vs;          // 1 MB
    u16* WoT  = Wall + 1024 * 512;// 0.5 MB
    const size_t need_fast = (size_t)(WoT + 512 * 512 - (u16*)d_ws) * sizeof(u16);

    if (ws_size >= need_fast) {
        prep<<<dim3(192), 256, 0, stream>>>(Wq, Wk, Wv, Wo, Wall, WoT);
        qkvX<<<dim3((BATCH * SEQ) / 128, 16), 256, 0, stream>>>(X, Wall, Qh, Kh, Vh);
        flash_mfma<<<dim3(32, NHEADS, BATCH), 512, 0, stream>>>(Qh, Kh, Vh, XA);
        oproj3<<<dim3((BATCH * SEQ) / 128, 8), 256, 0, stream>>>(XA, WoT, out);
    } else {
        u16* AOh = XA;
        qkv_proj<<<dim3(SEQ / 64, 16, BATCH), 256, 0, stream>>>(
            X, Wq, Wk, Wv, Qh, Kh, Vh);
        flash_mfma<<<dim3(32, NHEADS, BATCH), 512, 0, stream>>>(Qh, Kh, Vh, AOh);
        oproj_mfma<<<dim3((BATCH * SEQ) / 64, VDIM / 64), 256, 0, stream>>>(AOh, Wo, out);
    }
}

// Round 11
// 155.405 us; speedup vs baseline: 1.0091x; 1.0091x over previous
//
#include <hip/hip_runtime.h>
#include <hip/hip_bf16.h>
#include <math.h>

#define BATCH 2
#define CH 512
#define SEQ 4096
#define KDIM 256
#define VDIM 512
#define NHEADS 8
#define DK 32
#define DV 64

typedef unsigned short u16;
typedef unsigned int u32;
typedef __attribute__((ext_vector_type(8))) short bf16x8;
typedef __attribute__((ext_vector_type(4))) float f32x4;

__device__ __forceinline__ u16 f2bf(float f) {          // RNE
    u32 x = __float_as_uint(f);
    u32 r = (x + 0x7fffu + ((x >> 16) & 1u)) >> 16;
    return (u16)r;
}
__device__ __forceinline__ u16 f2bf_fast(float f) {     // half-up
    return (u16)((__float_as_uint(f) + 0x8000u) >> 16);
}
__device__ __forceinline__ u32 pack2f(float lo, float hi) {
    return (u32)f2bf_fast(lo) | (((__float_as_uint(hi) + 0x8000u) >> 16) << 16);
}
// v_cvt_pk_bf16_f32: D = {bf16(lo), bf16(hi)} (lo in low 16 bits), RNE.
__device__ __forceinline__ u32 cvtpk_bf16(float lo, float hi) {
    u32 r;
    asm("v_cvt_pk_bf16_f32 %0, %1, %2" : "=v"(r) : "v"(lo), "v"(hi));
    return r;
}

#define QSCALE (0.17677669529663687f * 1.4426950408889634f)  // 1/sqrt(dk)*log2e

// ===========================================================================
// FAST PATH — 3 kernels (prep deleted this round: weights staged from fp32
// directly inside qkvX/oproj3; 2.6MB of weights is L2-resident so the 64x
// cross-block re-read is cache-absorbed).
// ===========================================================================

// ---------------------------------------------------------------------------
// qkvX v4: round-9 validated 128x128 form (round-10's 128x64 regressed and
// is reverted) with ONE change: B-tile staged DIRECTLY from Wq/Wk/Wv fp32
// with transpose-on-stage — mirrors the validated A-from-X staging indices
// (cp/s4, two 64-wide chunks, pack2f at stride 40). QSCALE folded into the
// pack for Q (fallback-validated pattern). Removes prep + Wall round-trip.
// ---------------------------------------------------------------------------
#define ASW(row, colu16) ((row) * 40 + ((colu16) ^ ((((row) >> 2) & 3) << 3)))

__global__ __launch_bounds__(256, 2) void qkvX(
    const float* __restrict__ X,
    const float* __restrict__ Wq, const float* __restrict__ Wk,
    const float* __restrict__ Wv,
    u16* __restrict__ Qh, u16* __restrict__ Kh, u16* __restrict__ Vh)
{
    __shared__ __align__(16) u16 As[2][128 * 40];
    __shared__ __align__(16) u16 Bs[2][128 * 40];
    const int tid = threadIdx.x;
    const int wv = tid >> 6, lane = tid & 63;
    const int c = lane & 15, quad = lane >> 4;
    const int wm = wv & 1, wn = wv >> 1;
    const int m0 = blockIdx.x * 128;
    const int ny = blockIdx.y;           // 0..7 over concat N=1024

    u16* Y; int N; const float* Wf; int pitch, n0l; float scale = 1.0f;
    if (ny < 2)      { Y = Qh; N = KDIM; Wf = Wq; pitch = KDIM; n0l = ny * 128;       scale = QSCALE; }
    else if (ny < 4) { Y = Kh; N = KDIM; Wf = Wk; pitch = KDIM; n0l = (ny - 2) * 128; }
    else             { Y = Vh; N = VDIM; Wf = Wv; pitch = VDIM; n0l = (ny - 4) * 128; }

    // staging decomposition (round-9 validated): thread -> rows {2cp,2cp+1},
    // cols {s4..s4+3, 64+s4..64+s4+3}
    const int cp = tid >> 4;          // 0..15
    const int s4 = (tid & 15) * 4;    // 0..60
    const int bb = m0 >> 12;          // batch (tile never straddles)
    const float* Xb = X + (size_t)bb * CH * SEQ + (m0 & 4095);

    f32x4 acc[4][4];
#pragma unroll
    for (int i = 0; i < 4; ++i)
#pragma unroll
        for (int g = 0; g < 4; ++g) acc[i][g] = (f32x4){0.f, 0.f, 0.f, 0.f};

    float4 xa0, xb0, xa1, xb1;        // X rows 2cp,2cp+1 x col chunks
    float4 wa0, wb0, wa1, wb1;        // W rows 2cp,2cp+1 x col chunks
    auto ld = [&](int k0) {
        const size_t ch0 = (size_t)(k0 + 2 * cp) * SEQ;
        const size_t ch1 = ch0 + SEQ;
        xa0 = *reinterpret_cast<const float4*>(&Xb[ch0 + s4]);
        xb0 = *reinterpret_cast<const float4*>(&Xb[ch1 + s4]);
        xa1 = *reinterpret_cast<const float4*>(&Xb[ch0 + 64 + s4]);
        xb1 = *reinterpret_cast<const float4*>(&Xb[ch1 + 64 + s4]);
        const size_t wr0 = (size_t)(k0 + 2 * cp) * pitch + n0l;
        const size_t wr1 = wr0 + pitch;
        wa0 = *reinterpret_cast<const float4*>(&Wf[wr0 + s4]);
        wb0 = *reinterpret_cast<const float4*>(&Wf[wr1 + s4]);
        wa1 = *reinterpret_cast<const float4*>(&Wf[wr0 + 64 + s4]);
        wb1 = *reinterpret_cast<const float4*>(&Wf[wr1 + 64 + s4]);
    };
    auto stage = [&](int buf) {
        const float a0[4] = {xa0.x, xa0.y, xa0.z, xa0.w};
        const float b0[4] = {xb0.x, xb0.y, xb0.z, xb0.w};
        const float a1[4] = {xa1.x, xa1.y, xa1.z, xa1.w};
        const float b1[4] = {xb1.x, xb1.y, xb1.z, xb1.w};
        const float p0[4] = {wa0.x, wa0.y, wa0.z, wa0.w};
        const float q0[4] = {wb0.x, wb0.y, wb0.z, wb0.w};
        const float p1[4] = {wa1.x, wa1.y, wa1.z, wa1.w};
        const float q1[4] = {wb1.x, wb1.y, wb1.z, wb1.w};
#pragma unroll
        for (int i = 0; i < 4; ++i) {
            *reinterpret_cast<u32*>(&As[buf][ASW(s4 + i, 2 * cp)]) =
                pack2f(a0[i], b0[i]);
            *reinterpret_cast<u32*>(&As[buf][ASW(64 + s4 + i, 2 * cp)]) =
                pack2f(a1[i], b1[i]);
            *reinterpret_cast<u32*>(&Bs[buf][(s4 + i) * 40 + 2 * cp]) =
                pack2f(p0[i] * scale, q0[i] * scale);
            *reinterpret_cast<u32*>(&Bs[buf][(64 + s4 + i) * 40 + 2 * cp]) =
                pack2f(p1[i] * scale, q1[i] * scale);
        }
    };

    ld(0);
    stage(0);
    ld(32);

    for (int i = 0; i < 16; ++i) {
        const int cur = i & 1;
        __syncthreads();
        stage(cur ^ 1);
        const int k0n = (i + 2 < 16) ? (i + 2) * 32 : 15 * 32;
        ld(k0n);
        bf16x8 af[4], bf_[4];
#pragma unroll
        for (int j = 0; j < 4; ++j) {
            af[j] = *reinterpret_cast<bf16x8*>(
                &As[cur][ASW(wm * 64 + 16 * j + c, quad * 8)]);
            bf_[j] = *reinterpret_cast<bf16x8*>(
                &Bs[cur][(wn * 64 + 16 * j + c) * 40 + quad * 8]);
        }
#pragma unroll
        for (int j = 0; j < 4; ++j)
#pragma unroll
            for (int g = 0; g < 4; ++g)
                acc[j][g] = __builtin_amdgcn_mfma_f32_16x16x32_bf16(
                    af[j], bf_[g], acc[j][g], 0, 0, 0);
    }
#pragma unroll
    for (int j = 0; j < 4; ++j)
#pragma unroll
        for (int r = 0; r < 4; ++r) {
            const int row = m0 + wm * 64 + 16 * j + quad * 4 + r;
            const int col = n0l + wn * 64 + c;
#pragma unroll
            for (int g = 0; g < 4; ++g)
                Y[(size_t)row * N + col + 16 * g] = f2bf(acc[j][g][r]);
        }
}

// ---------------------------------------------------------------------------
// oproj3 v3: round-7/9 validated 128x64 geometry with ONE change: B-tile
// staged DIRECTLY from Wo fp32 — byte-for-byte the validated fallback
// oproj_mfma ldwf/stage pattern (kp/n4, pack2f at stride 40). Removes WoT.
// ---------------------------------------------------------------------------
__global__ __launch_bounds__(256, 2) void oproj3(
    const u16* __restrict__ A, const float* __restrict__ Wo,
    float* __restrict__ Out)
{
    __shared__ __align__(16) u16 As[2][128 * 40];
    __shared__ __align__(16) u16 Bs[2][64 * 40];
    const int tid = threadIdx.x;
    const int wv = tid >> 6, lane = tid & 63;
    const int c = lane & 15, quad = lane >> 4;
    const int wm = wv & 1, wn = wv >> 1;
    const int m0 = blockIdx.x * 128;
    const int n0 = blockIdx.y * 64;

    const int srow = tid >> 1, scol = (tid & 1) * 16;   // A staging
    const int kp = tid >> 4;          // B staging (oproj_mfma validated)
    const int n4 = (tid & 15) * 4;

    f32x4 acc[4][2];
#pragma unroll
    for (int j = 0; j < 4; ++j)
#pragma unroll
        for (int g = 0; g < 2; ++g) acc[j][g] = (f32x4){0.f, 0.f, 0.f, 0.f};

    uint4 ar0, ar1;
    float4 wa, wb;
    auto ld = [&](int k0) {
        const uint4* ap = reinterpret_cast<const uint4*>(
            &A[(size_t)(m0 + srow) * 512 + k0 + scol]);
        ar0 = ap[0]; ar1 = ap[1];
        wa = *reinterpret_cast<const float4*>(
            &Wo[(size_t)(k0 + 2 * kp) * 512 + n0 + n4]);
        wb = *reinterpret_cast<const float4*>(
            &Wo[(size_t)(k0 + 2 * kp + 1) * 512 + n0 + n4]);
    };
    auto stage = [&](int buf) {
        uint4* ad = reinterpret_cast<uint4*>(&As[buf][srow * 40 + scol]);
        ad[0] = ar0; ad[1] = ar1;
        const float a[4] = {wa.x, wa.y, wa.z, wa.w};
        const float bb[4] = {wb.x, wb.y, wb.z, wb.w};
#pragma unroll
        for (int i = 0; i < 4; ++i)
            *reinterpret_cast<u32*>(&Bs[buf][(n4 + i) * 40 + 2 * kp]) =
                pack2f(a[i], bb[i]);
    };

    ld(0);
    stage(0);
    ld(32);

    for (int i = 0; i < 16; ++i) {
        const int cur = i & 1;
        __syncthreads();
        stage(cur ^ 1);
        const int k0n = (i + 2 < 16) ? (i + 2) * 32 : 15 * 32;
        ld(k0n);
        bf16x8 af[4], bf_[2];
#pragma unroll
        for (int j = 0; j < 4; ++j)
            af[j] = *reinterpret_cast<bf16x8*>(
                &As[cur][(wm * 64 + 16 * j + c) * 40 + quad * 8]);
#pragma unroll
        for (int g = 0; g < 2; ++g)
            bf_[g] = *reinterpret_cast<bf16x8*>(
                &Bs[cur][(wn * 32 + 16 * g + c) * 40 + quad * 8]);
#pragma unroll
        for (int j = 0; j < 4; ++j)
#pragma unroll
            for (int g = 0; g < 2; ++g)
                acc[j][g] = __builtin_amdgcn_mfma_f32_16x16x32_bf16(
                    af[j], bf_[g], acc[j][g], 0, 0, 0);
    }
#pragma unroll
    for (int j = 0; j < 4; ++j)
#pragma unroll
        for (int r = 0; r < 4; ++r) {
            const int row = m0 + wm * 64 + 16 * j + quad * 4 + r;
            const int col = n0 + wn * 32 + c;
#pragma unroll
            for (int g = 0; g < 2; ++g)
                Out[(size_t)row * 512 + col + 16 * g] = acc[j][g][r];
        }
}

// ===========================================================================
// flash v15 (round-5/7/9 validated text, UNCHANGED): paired A/B q-blocks,
// T12 in-register P transform, XOR-swizzled unpadded K/V tiles. ~57us,
// absmax 0.015625. Un-paired variant failed correctness twice — do not
// re-attempt without a device-side debugging path.
// ===========================================================================
#define KSW(row, col) ((row) * 32 + ((col) ^ (((row) & 3) << 3)))
#define VSW(row, col) ((row) * 64 + ((col) ^ (((row) & 7) << 3)))

__global__ __launch_bounds__(512, 4) void flash_mfma(
    const u16* __restrict__ Q, const u16* __restrict__ K,
    const u16* __restrict__ V, u16* __restrict__ AO)
{
    __shared__ __align__(16) union {
        struct {
            u16 Kl[2][2][64 * 32];
            u16 Vt[2][2][64 * 64];
        } t;
        float mg[4][64][40];
    } sh;

    const int tid  = threadIdx.x;
    const int w    = tid >> 6;
    const int ws   = w & 3;
    const int wg   = w >> 2;
    const int lane = tid & 63;
    const int c    = lane & 15;
    const int quad = lane >> 4;
    const int h = blockIdx.y, b = blockIdx.z;

    const int qbA = blockIdx.x;
    const int qbB = 63 - qbA;
    const int q0A = qbA * 64, q0B = qbB * 64;

    const u16* Qb = Q + (size_t)b * SEQ * KDIM + h * DK;
    const u16* Kb = K + (size_t)b * SEQ * KDIM + h * DK;
    const u16* Vb = V + (size_t)b * SEQ * VDIM + h * DV;
    u16* AOb = AO + (size_t)b * SEQ * VDIM + h * DV;

    const bf16x8 qfA = *reinterpret_cast<const bf16x8*>(
        &Qb[(size_t)(q0A + ws * 16 + c) * KDIM + quad * 8]);
    const bf16x8 qfB = *reinterpret_cast<const bf16x8*>(
        &Qb[(size_t)(q0B + ws * 16 + c) * KDIM + quad * 8]);

    // constant all-ones A-frag: bf16 1.0 = 0x3F80 in every element
    const bf16x8 ones = {(short)0x3F80, (short)0x3F80, (short)0x3F80, (short)0x3F80,
                         (short)0x3F80, (short)0x3F80, (short)0x3F80, (short)0x3F80};

    f32x4 oA[4], oB[4];
#pragma unroll
    for (int g = 0; g < 4; ++g) {
        oA[g] = (f32x4){0.f, 0.f, 0.f, 0.f};
        oB[g] = (f32x4){0.f, 0.f, 0.f, 0.f};
    }
    f32x4 laccA = {0.f, 0.f, 0.f, 0.f}, laccB = {0.f, 0.f, 0.f, 0.f};

    const int t256 = tid & 255;
    const int krow = t256 >> 2, kc8 = (t256 & 3) * 8;
    const int vs0 = (t256 & 31) * 2, vd0 = (t256 >> 5) * 8;

    const int qrbase = ws * 16 + c;   // per-lane q row (within q-block)
    const int T = (qbB >> 1) + 1;

    uint4 kreg, vra, vrb;
    auto ldtile = [&](int kb) {
        const int k0 = kb * 64;
        kreg = *reinterpret_cast<const uint4*>(&Kb[(size_t)(k0 + krow) * KDIM + kc8]);
        vra  = *reinterpret_cast<const uint4*>(&Vb[(size_t)(k0 + vs0) * VDIM + vd0]);
        vrb  = *reinterpret_cast<const uint4*>(&Vb[(size_t)(k0 + vs0 + 1) * VDIM + vd0]);
    };
    auto stagetile = [&](int buf) {
        *reinterpret_cast<uint4*>(&sh.t.Kl[wg][buf][KSW(krow, kc8)]) = kreg;
        union { uint4 q; u16 s[8]; } ra, rb;
        ra.q = vra; rb.q = vrb;
#pragma unroll
        for (int i = 0; i < 8; ++i) {
            u32 packed = (u32)ra.s[i] | ((u32)rb.s[i] << 16);
            *reinterpret_cast<u32*>(&sh.t.Vt[wg][buf][VSW(vd0 + i, vs0)]) = packed;
        }
    };

    ldtile(wg);
    stagetile(0);
    ldtile(2 + wg);

    for (int it = 0; it < T; ++it) {
        const int kb = 2 * it + wg;
        const int k0 = kb * 64;
        const int cur = it & 1;
        __syncthreads();
        stagetile(cur ^ 1);
        {
            int kbn = 2 * (it + 2) + wg; if (kbn > 63) kbn = 63;
            ldtile(kbn);
        }
        const u16* Klc = sh.t.Kl[wg][cur];
        const u16* Vtc = sh.t.Vt[wg][cur];

        auto compute = [&](const bf16x8& qf, int q0, bool diag,
                           f32x4* o, f32x4& lacc) {
            // swapped QK^T: lane(c,quad) gets S[q=c][k=16g+quad*4+r]
            f32x4 s[4];
#pragma unroll
            for (int g = 0; g < 4; ++g) {
                const bf16x8 kf = *reinterpret_cast<const bf16x8*>(
                    &Klc[KSW(c + 16 * g, quad * 8)]);
                const f32x4 z = {0.f, 0.f, 0.f, 0.f};
                s[g] = __builtin_amdgcn_mfma_f32_16x16x32_bf16(kf, qf, z, 0, 0, 0);
            }
            if (diag) {
                const int qr = q0 + qrbase;
#pragma unroll
                for (int g = 0; g < 4; ++g) {
                    const int kc0 = k0 + 16 * g + quad * 4;
#pragma unroll
                    for (int r = 0; r < 4; ++r)
                        if (kc0 + r > qr) s[g][r] = -1e30f;
                }
            }
            // exp2 + pack: wk[g][j2] covers k = quad*4 + 16g + 2*j2 + {0,1}
            u32 wk[4][2];
#pragma unroll
            for (int g = 0; g < 4; ++g)
#pragma unroll
                for (int j2 = 0; j2 < 2; ++j2)
                    wk[g][j2] = cvtpk_bf16(
                        __builtin_amdgcn_exp2f(s[g][2 * j2]),
                        __builtin_amdgcn_exp2f(s[g][2 * j2 + 1]));
            // permutation network -> PV B-frags pb0 (k 0..31), pb1 (k 32..63)
            union { u32 wq[4]; bf16x8 v; } ub0, ub1;
#pragma unroll
            for (int j2 = 0; j2 < 2; ++j2) {
                {
                    auto t1 = __builtin_amdgcn_permlane32_swap(
                        wk[0][j2], wk[1][j2], false, false);
                    auto t2 = __builtin_amdgcn_permlane16_swap(
                        (u32)t1[0], (u32)t1[1], false, false);
                    ub0.wq[j2]     = (u32)t2[0];
                    ub0.wq[2 + j2] = (u32)t2[1];
                }
                {
                    auto t1 = __builtin_amdgcn_permlane32_swap(
                        wk[2][j2], wk[3][j2], false, false);
                    auto t2 = __builtin_amdgcn_permlane16_swap(
                        (u32)t1[0], (u32)t1[1], false, false);
                    ub1.wq[j2]     = (u32)t2[0];
                    ub1.wq[2 + j2] = (u32)t2[1];
                }
            }
            const bf16x8 pb0 = ub0.v, pb1 = ub1.v;
            // rowsum via matrix pipe: every reg of lacc holds l[q=c]
            lacc = __builtin_amdgcn_mfma_f32_16x16x32_bf16(ones, pb0, lacc, 0, 0, 0);
            lacc = __builtin_amdgcn_mfma_f32_16x16x32_bf16(ones, pb1, lacc, 0, 0, 0);
            // PV (transposed): o[g] holds O[q=c][dv=16g+quad*4+r]
#pragma unroll
            for (int g = 0; g < 4; ++g) {
                const bf16x8 v0 = *reinterpret_cast<const bf16x8*>(
                    &Vtc[VSW(c + 16 * g, quad * 8)]);
                const bf16x8 v1 = *reinterpret_cast<const bf16x8*>(
                    &Vtc[VSW(c + 16 * g, 32 + quad * 8)]);
                o[g] = __builtin_amdgcn_mfma_f32_16x16x32_bf16(v0, pb0, o[g], 0, 0, 0);
                o[g] = __builtin_amdgcn_mfma_f32_16x16x32_bf16(v1, pb1, o[g], 0, 0, 0);
            }
        };

        if (kb <= qbA) compute(qfA, q0A, kb == qbA, oA, laccA);
        if (kb <= qbB) compute(qfB, q0B, kb == qbB, oB, laccB);
    }

    __syncthreads();
    if (wg == 1) {
        float* m = sh.mg[ws][lane];
#pragma unroll
        for (int g = 0; g < 4; ++g)
#pragma unroll
            for (int r = 0; r < 4; ++r) {
                m[g * 4 + r]      = oA[g][r];
                m[16 + g * 4 + r] = oB[g][r];
            }
        m[32] = laccA[0];
        m[33] = laccB[0];
    }
    __syncthreads();
    if (wg == 0) {
        const float* m = sh.mg[ws][lane];
#pragma unroll
        for (int g = 0; g < 4; ++g)
#pragma unroll
            for (int r = 0; r < 4; ++r) {
                oA[g][r] += m[g * 4 + r];
                oB[g][r] += m[16 + g * 4 + r];
            }
        const float invA = 1.f / (laccA[0] + m[32]);
        const float invB = 1.f / (laccB[0] + m[33]);
        const int rowA = q0A + qrbase;
        const int rowB = q0B + qrbase;
#pragma unroll
        for (int g = 0; g < 4; ++g) {
            ushort4 a4, b4;
            a4.x = f2bf(oA[g][0] * invA); a4.y = f2bf(oA[g][1] * invA);
            a4.z = f2bf(oA[g][2] * invA); a4.w = f2bf(oA[g][3] * invA);
            b4.x = f2bf(oB[g][0] * invB); b4.y = f2bf(oB[g][1] * invB);
            b4.z = f2bf(oB[g][2] * invB); b4.w = f2bf(oB[g][3] * invB);
            *reinterpret_cast<ushort4*>(
                &AOb[(size_t)rowA * VDIM + 16 * g + quad * 4]) = a4;
            *reinterpret_cast<ushort4*>(
                &AOb[(size_t)rowB * VDIM + 16 * g + quad * 4]) = b4;
        }
    }
}

// ===========================================================================
// FALLBACK PATH (ws too small): round-10 projection kernels
// ===========================================================================
__global__ __launch_bounds__(256) void qkv_proj(
    const float* __restrict__ X,
    const float* __restrict__ Wq, const float* __restrict__ Wk,
    const float* __restrict__ Wv,
    u16* __restrict__ Qh, u16* __restrict__ Kh, u16* __restrict__ Vh)
{
    __shared__ __align__(16) u16 Xs[2][64 * 40];
    __shared__ __align__(16) u16 Wsm[2][64 * 40];
    const int tid = threadIdx.x;
    const int w = tid >> 6, lane = tid & 63;
    const int c = lane & 15, quad = lane >> 4;
    const int s0 = blockIdx.x * 64, b = blockIdx.z;
    const int ny = blockIdx.y;

    const float* Wt; u16* Y; int N, n0; float scale;
    if (ny < 4)       { Wt = Wq; Y = Qh; N = KDIM; n0 = ny * 64;       scale = QSCALE; }
    else if (ny < 8)  { Wt = Wk; Y = Kh; N = KDIM; n0 = (ny - 4) * 64; scale = 1.0f; }
    else              { Wt = Wv; Y = Vh; N = VDIM; n0 = (ny - 8) * 64; scale = 1.0f; }

    const float* Xb = X + (size_t)b * CH * SEQ;
    const int cp = tid >> 4;
    const int s4 = (tid & 15) * 4;

    f32x4 acc[4];
#pragma unroll
    for (int g = 0; g < 4; ++g) acc[g] = (f32x4){0.f, 0.f, 0.f, 0.f};

    auto ldx = [&](int c0, float4& a, float4& bb) {
        a  = *reinterpret_cast<const float4*>(&Xb[(size_t)(c0 + 2 * cp) * SEQ + s0 + s4]);
        bb = *reinterpret_cast<const float4*>(&Xb[(size_t)(c0 + 2 * cp + 1) * SEQ + s0 + s4]);
    };
    auto ldwf = [&](int c0, float4& a, float4& bb) {
        a  = *reinterpret_cast<const float4*>(&Wt[(size_t)(c0 + 2 * cp) * N + n0 + s4]);
        bb = *reinterpret_cast<const float4*>(&Wt[(size_t)(c0 + 2 * cp + 1) * N + n0 + s4]);
    };
    auto stage = [&](int buf, const float4& xa, const float4& xb,
                     const float4& wa, const float4& wb) {
        const float a[4] = {xa.x, xa.y, xa.z, xa.w};
        const float bb[4] = {xb.x, xb.y, xb.z, xb.w};
        const float aw[4] = {wa.x, wa.y, wa.z, wa.w};
        const float bw[4] = {wb.x, wb.y, wb.z, wb.w};
#pragma unroll
        for (int i = 0; i < 4; ++i) {
            *reinterpret_cast<u32*>(&Xs[buf][(s4 + i) * 40 + 2 * cp]) = pack2f(a[i], bb[i]);
            *reinterpret_cast<u32*>(&Wsm[buf][(s4 + i) * 40 + 2 * cp]) = pack2f(aw[i] * scale, bw[i] * scale);
        }
    };

    float4 xa, xb, wa, wb;
    ldx(0, xa, xb); ldwf(0, wa, wb);
    stage(0, xa, xb, wa, wb);
    ldx(32, xa, xb); ldwf(32, wa, wb);

    for (int i = 0; i < 16; ++i) {
        const int cur = i & 1;
        __syncthreads();
        stage(cur ^ 1, xa, xb, wa, wb);
        const int c0n = (i + 2 < 16) ? (i + 2) * 32 : 15 * 32;
        ldx(c0n, xa, xb); ldwf(c0n, wa, wb);
        const bf16x8 af = *reinterpret_cast<bf16x8*>(&Xs[cur][(w * 16 + c) * 40 + quad * 8]);
#pragma unroll
        for (int g = 0; g < 4; ++g) {
            bf16x8 bf_ = *reinterpret_cast<bf16x8*>(&Wsm[cur][(c + 16 * g) * 40 + quad * 8]);
            acc[g] = __builtin_amdgcn_mfma_f32_16x16x32_bf16(af, bf_, acc[g], 0, 0, 0);
        }
    }
    u16* Yb = Y + (size_t)b * SEQ * N;
#pragma unroll
    for (int r = 0; r < 4; ++r) {
        const int row = s0 + w * 16 + quad * 4 + r;
#pragma unroll
        for (int g = 0; g < 4; ++g)
            Yb[(size_t)row * N + n0 + c + 16 * g] = f2bf(acc[g][r]);
    }
}

__global__ __launch_bounds__(256) void oproj_mfma(
    const u16* __restrict__ A, const float* __restrict__ Wo,
    float* __restrict__ Out)
{
    __shared__ __align__(16) u16 Ws[2][64 * 40];
    const int tid = threadIdx.x;
    const int w = tid >> 6, lane = tid & 63;
    const int c = lane & 15, quad = lane >> 4;
    const int m0 = blockIdx.x * 64, n0 = blockIdx.y * 64;
    const int kp = tid >> 4;
    const int n4 = (tid & 15) * 4;
    const u16* Arow = &A[(size_t)(m0 + w * 16 + c) * 512];

    f32x4 acc[4];
#pragma unroll
    for (int g = 0; g < 4; ++g) acc[g] = (f32x4){0.f, 0.f, 0.f, 0.f};

    auto ldwf = [&](int k0, float4& a, float4& bb) {
        a  = *reinterpret_cast<const float4*>(&Wo[(size_t)(k0 + 2 * kp) * 512 + n0 + n4]);
        bb = *reinterpret_cast<const float4*>(&Wo[(size_t)(k0 + 2 * kp + 1) * 512 + n0 + n4]);
    };
    auto stage = [&](int buf, const float4& wa, const float4& wb) {
        const float a[4] = {wa.x, wa.y, wa.z, wa.w};
        const float bb[4] = {wb.x, wb.y, wb.z, wb.w};
#pragma unroll
        for (int i = 0; i < 4; ++i)
            *reinterpret_cast<u32*>(&Ws[buf][(n4 + i) * 40 + 2 * kp]) = pack2f(a[i], bb[i]);
    };

    float4 wa, wb;
    ldwf(0, wa, wb);
    stage(0, wa, wb);
    ldwf(32, wa, wb);
    bf16x8 afc = *reinterpret_cast<const bf16x8*>(&Arow[quad * 8]);

    for (int i = 0; i < 16; ++i) {
        const int cur = i & 1;
        __syncthreads();
        stage(cur ^ 1, wa, wb);
        const int k0n = (i + 2 < 16) ? (i + 2) * 32 : 15 * 32;
        ldwf(k0n, wa, wb);
        const int k0a = (i + 1 < 16) ? (i + 1) * 32 : 15 * 32;
        const bf16x8 afn = *reinterpret_cast<const bf16x8*>(&Arow[k0a + quad * 8]);
#pragma unroll
        for (int g = 0; g < 4; ++g) {
            bf16x8 bf_ = *reinterpret_cast<bf16x8*>(&Ws[cur][(c + 16 * g) * 40 + quad * 8]);
            acc[g] = __builtin_amdgcn_mfma_f32_16x16x32_bf16(afc, bf_, acc[g], 0, 0, 0);
        }
        afc = afn;
    }
#pragma unroll
    for (int r = 0; r < 4; ++r) {
        const int row = m0 + w * 16 + quad * 4 + r;
#pragma unroll
        for (int g = 0; g < 4; ++g)
            Out[(size_t)row * 512 + n0 + c + 16 * g] = acc[g][r];
    }
}

extern "C" void kernel_launch(void* const* d_in, const int* in_sizes, int n_in,
                              void* d_out, int out_size, void* d_ws, size_t ws_size,
                              hipStream_t stream) {
    const float* X  = (const float*)d_in[0];
    const float* Wq = (const float*)d_in[1];
    const float* Wk = (const float*)d_in[2];
    const float* Wv = (const float*)d_in[3];
    const float* Wo = (const float*)d_in[4];
    float* out = (float*)d_out;

    const size_t qk = (size_t)BATCH * SEQ * KDIM;
    const size_t vs = (size_t)BATCH * SEQ * VDIM;
    u16* Qh  = (u16*)d_ws;        // 4 MB
    u16* Kh  = Qh + qk;           // 4 MB
    u16* Vh  = Kh + qk;           // 8 MB
    u16* XA  = Vh + vs;           // 8 MB: AO after flash
    const size_t need_fast = (size_t)(XA + vs - (u16*)d_ws) * sizeof(u16);

    if (ws_size >= need_fast) {
        qkvX<<<dim3((BATCH * SEQ) / 128, 8), 256, 0, stream>>>(
            X, Wq, Wk, Wv, Qh, Kh, Vh);
        flash_mfma<<<dim3(32, NHEADS, BATCH), 512, 0, stream>>>(Qh, Kh, Vh, XA);
        oproj3<<<dim3((BATCH * SEQ) / 128, 8), 256, 0, stream>>>(XA, Wo, out);
    } else {
        u16* AOh = XA;
        qkv_proj<<<dim3(SEQ / 64, 16, BATCH), 256, 0, stream>>>(
            X, Wq, Wk, Wv, Qh, Kh, Vh);
        flash_mfma<<<dim3(32, NHEADS, BATCH), 512, 0, stream>>>(Qh, Kh, Vh, AOh);
        oproj_mfma<<<dim3((BATCH * SEQ) / 64, VDIM / 64), 256, 0, stream>>>(AOh, Wo, out);
    }
}

// Round 13
// 151.394 us; speedup vs baseline: 1.0358x; 1.0265x over previous
//
#include <hip/hip_runtime.h>
#include <hip/hip_bf16.h>
#include <math.h>

#define BATCH 2
#define CH 512
#define SEQ 4096
#define KDIM 256
#define VDIM 512
#define NHEADS 8
#define DK 32
#define DV 64

typedef unsigned short u16;
typedef unsigned int u32;
typedef __attribute__((ext_vector_type(8))) short bf16x8;
typedef __attribute__((ext_vector_type(4))) float f32x4;

__device__ __forceinline__ u16 f2bf(float f) {          // RNE
    u32 x = __float_as_uint(f);
    u32 r = (x + 0x7fffu + ((x >> 16) & 1u)) >> 16;
    return (u16)r;
}
__device__ __forceinline__ u16 f2bf_fast(float f) {     // half-up
    return (u16)((__float_as_uint(f) + 0x8000u) >> 16);
}
__device__ __forceinline__ u32 pack2f(float lo, float hi) {
    return (u32)f2bf_fast(lo) | (((__float_as_uint(hi) + 0x8000u) >> 16) << 16);
}
// v_cvt_pk_bf16_f32: D = {bf16(lo), bf16(hi)} (lo in low 16 bits), RNE.
__device__ __forceinline__ u32 cvtpk_bf16(float lo, float hi) {
    u32 r;
    asm("v_cvt_pk_bf16_f32 %0, %1, %2" : "=v"(r) : "v"(lo), "v"(hi));
    return r;
}

#define QSCALE (0.17677669529663687f * 1.4426950408889634f)  // 1/sqrt(dk)*log2e

// ===========================================================================
// FAST PATH (round-9 best-measured configuration, 151.97us)
// ===========================================================================

// prep v2 (round-9 validated): WEIGHTS ONLY.
// 192 blocks: bid<128 -> Wall (Wq|Wk|Wv, Q pre-scaled), else -> WoT.
__global__ __launch_bounds__(256) void prep(
    const float* __restrict__ Wq, const float* __restrict__ Wk,
    const float* __restrict__ Wv, const float* __restrict__ Wo,
    u16* __restrict__ Wall, u16* __restrict__ WoT)
{
    __shared__ u16 T[64 * 72];
    const int bid = blockIdx.x;
    const int t = threadIdx.x;
    const int tr = t >> 4;
    const int tc4 = (t & 15) * 4;

    const float* src; u16* dst;
    int src_row0, src_col0, src_pitch, dst_row0, dst_col0, dst_pitch;
    float scale = 1.0f;

    if (bid < 128) {
        const int nt = bid >> 3, ct = bid & 7;
        if (nt < 4)      { src = Wq; src_col0 = nt * 64;       src_pitch = KDIM; scale = QSCALE; }
        else if (nt < 8) { src = Wk; src_col0 = (nt - 4) * 64; src_pitch = KDIM; }
        else             { src = Wv; src_col0 = (nt - 8) * 64; src_pitch = VDIM; }
        src_row0 = ct * 64;
        dst = Wall; dst_row0 = nt * 64; dst_col0 = ct * 64; dst_pitch = 512;
    } else {
        const int r = bid - 128;
        const int kt = r >> 3, nt = r & 7;
        src = Wo; src_row0 = kt * 64; src_col0 = nt * 64; src_pitch = 512;
        dst = WoT; dst_row0 = nt * 64; dst_col0 = kt * 64; dst_pitch = 512;
    }

#pragma unroll
    for (int j = 0; j < 4; ++j) {
        const int row = j * 16 + tr;
        const float4 v = *reinterpret_cast<const float4*>(
            &src[(size_t)(src_row0 + row) * src_pitch + src_col0 + tc4]);
        T[(tc4 + 0) * 72 + row] = f2bf(v.x * scale);
        T[(tc4 + 1) * 72 + row] = f2bf(v.y * scale);
        T[(tc4 + 2) * 72 + row] = f2bf(v.z * scale);
        T[(tc4 + 3) * 72 + row] = f2bf(v.w * scale);
    }
    __syncthreads();
#pragma unroll
    for (int j = 0; j < 4; ++j) {
        const int orow = j * 16 + tr;
        const ushort4 o = *reinterpret_cast<ushort4*>(&T[orow * 72 + tc4]);
        *reinterpret_cast<ushort4*>(
            &dst[(size_t)(dst_row0 + orow) * dst_pitch + dst_col0 + tc4]) = o;
    }
}

// ---------------------------------------------------------------------------
// qkvX (round-9 validated): 128x128-tile GEMM, A-tile staged DIRECTLY from
// X fp32 (transpose-on-stage), B-tile from pre-transposed Wall bf16.
// A-store swizzle ASW: col ^= ((row>>2)&3)<<3.
// ---------------------------------------------------------------------------
#define ASW(row, colu16) ((row) * 40 + ((colu16) ^ ((((row) >> 2) & 3) << 3)))

__global__ __launch_bounds__(256, 2) void qkvX(
    const float* __restrict__ X, const u16* __restrict__ Wall,
    u16* __restrict__ Qh, u16* __restrict__ Kh, u16* __restrict__ Vh)
{
    __shared__ __align__(16) u16 As[2][128 * 40];
    __shared__ __align__(16) u16 Bs[2][128 * 40];
    const int tid = threadIdx.x;
    const int wv = tid >> 6, lane = tid & 63;
    const int c = lane & 15, quad = lane >> 4;
    const int wm = wv & 1, wn = wv >> 1;
    const int m0 = blockIdx.x * 128;
    const int ny = blockIdx.y;           // 0..7 over concat N
    const int n0 = ny * 128;

    u16* Y; int N, nbase;
    if (ny < 2)      { Y = Qh; N = KDIM; nbase = 0; }
    else if (ny < 4) { Y = Kh; N = KDIM; nbase = 256; }
    else             { Y = Vh; N = VDIM; nbase = 512; }

    // A staging: thread -> channels {2cp, 2cp+1}, s-rows {s4..s4+3, 64+s4..}
    const int cp = tid >> 4;          // 0..15
    const int s4 = (tid & 15) * 4;    // 0..60
    const int bb = m0 >> 12;          // batch (tile never straddles)
    const float* Xb = X + (size_t)bb * CH * SEQ + (m0 & 4095);

    // B staging (qkv3 validated)
    const int srow = tid >> 1, scol = (tid & 1) * 16;

    f32x4 acc[4][4];
#pragma unroll
    for (int i = 0; i < 4; ++i)
#pragma unroll
        for (int g = 0; g < 4; ++g) acc[i][g] = (f32x4){0.f, 0.f, 0.f, 0.f};

    float4 xa0, xb0, xa1, xb1;
    uint4 br0, br1;
    auto ld = [&](int k0) {
        const size_t ch0 = (size_t)(k0 + 2 * cp) * SEQ;
        const size_t ch1 = (size_t)(k0 + 2 * cp + 1) * SEQ;
        xa0 = *reinterpret_cast<const float4*>(&Xb[ch0 + s4]);
        xb0 = *reinterpret_cast<const float4*>(&Xb[ch1 + s4]);
        xa1 = *reinterpret_cast<const float4*>(&Xb[ch0 + 64 + s4]);
        xb1 = *reinterpret_cast<const float4*>(&Xb[ch1 + 64 + s4]);
        const uint4* bp = reinterpret_cast<const uint4*>(
            &Wall[(size_t)(n0 + srow) * 512 + k0 + scol]);
        br0 = bp[0]; br1 = bp[1];
    };
    auto stage = [&](int buf) {
        const float a0[4] = {xa0.x, xa0.y, xa0.z, xa0.w};
        const float b0[4] = {xb0.x, xb0.y, xb0.z, xb0.w};
        const float a1[4] = {xa1.x, xa1.y, xa1.z, xa1.w};
        const float b1[4] = {xb1.x, xb1.y, xb1.z, xb1.w};
#pragma unroll
        for (int i = 0; i < 4; ++i) {
            *reinterpret_cast<u32*>(&As[buf][ASW(s4 + i, 2 * cp)]) =
                pack2f(a0[i], b0[i]);
            *reinterpret_cast<u32*>(&As[buf][ASW(64 + s4 + i, 2 * cp)]) =
                pack2f(a1[i], b1[i]);
        }
        uint4* bd = reinterpret_cast<uint4*>(&Bs[buf][srow * 40 + scol]);
        bd[0] = br0; bd[1] = br1;
    };

    ld(0);
    stage(0);
    ld(32);

    for (int i = 0; i < 16; ++i) {
        const int cur = i & 1;
        __syncthreads();
        stage(cur ^ 1);
        const int k0n = (i + 2 < 16) ? (i + 2) * 32 : 15 * 32;
        ld(k0n);
        bf16x8 af[4], bf_[4];
#pragma unroll
        for (int j = 0; j < 4; ++j) {
            af[j] = *reinterpret_cast<bf16x8*>(
                &As[cur][ASW(wm * 64 + 16 * j + c, quad * 8)]);
            bf_[j] = *reinterpret_cast<bf16x8*>(
                &Bs[cur][(wn * 64 + 16 * j + c) * 40 + quad * 8]);
        }
#pragma unroll
        for (int j = 0; j < 4; ++j)
#pragma unroll
            for (int g = 0; g < 4; ++g)
                acc[j][g] = __builtin_amdgcn_mfma_f32_16x16x32_bf16(
                    af[j], bf_[g], acc[j][g], 0, 0, 0);
    }
#pragma unroll
    for (int j = 0; j < 4; ++j)
#pragma unroll
        for (int r = 0; r < 4; ++r) {
            const int row = m0 + wm * 64 + 16 * j + quad * 4 + r;
            const int col = n0 - nbase + wn * 64 + c;
#pragma unroll
            for (int g = 0; g < 4; ++g)
                Y[(size_t)row * N + col + 16 * g] = f2bf(acc[j][g][r]);
        }
}

// ---------------------------------------------------------------------------
// oproj3 v2 (round-7/9 validated): 128x64-tile GEMM, grid (64,8) = 512 blocks.
// ---------------------------------------------------------------------------
__global__ __launch_bounds__(256, 2) void oproj3(
    const u16* __restrict__ A, const u16* __restrict__ WoT,
    float* __restrict__ Out)
{
    __shared__ __align__(16) u16 As[2][128 * 40];
    __shared__ __align__(16) u16 Bs[2][64 * 40];
    const int tid = threadIdx.x;
    const int wv = tid >> 6, lane = tid & 63;
    const int c = lane & 15, quad = lane >> 4;
    const int wm = wv & 1, wn = wv >> 1;
    const int m0 = blockIdx.x * 128;
    const int n0 = blockIdx.y * 64;

    const int srow = tid >> 1, scol = (tid & 1) * 16;   // A staging
    const int srB = tid >> 2, scB = (tid & 3) * 8;      // B staging (1 uint4/thread)

    f32x4 acc[4][2];
#pragma unroll
    for (int j = 0; j < 4; ++j)
#pragma unroll
        for (int g = 0; g < 2; ++g) acc[j][g] = (f32x4){0.f, 0.f, 0.f, 0.f};

    uint4 ar0, ar1, br0;
    auto ld = [&](int k0) {
        const uint4* ap = reinterpret_cast<const uint4*>(
            &A[(size_t)(m0 + srow) * 512 + k0 + scol]);
        ar0 = ap[0]; ar1 = ap[1];
        br0 = *reinterpret_cast<const uint4*>(
            &WoT[(size_t)(n0 + srB) * 512 + k0 + scB]);
    };
    auto stage = [&](int buf) {
        uint4* ad = reinterpret_cast<uint4*>(&As[buf][srow * 40 + scol]);
        ad[0] = ar0; ad[1] = ar1;
        *reinterpret_cast<uint4*>(&Bs[buf][srB * 40 + scB]) = br0;
    };

    ld(0);
    stage(0);
    ld(32);

    for (int i = 0; i < 16; ++i) {
        const int cur = i & 1;
        __syncthreads();
        stage(cur ^ 1);
        const int k0n = (i + 2 < 16) ? (i + 2) * 32 : 15 * 32;
        ld(k0n);
        bf16x8 af[4], bf_[2];
#pragma unroll
        for (int j = 0; j < 4; ++j)
            af[j] = *reinterpret_cast<bf16x8*>(
                &As[cur][(wm * 64 + 16 * j + c) * 40 + quad * 8]);
#pragma unroll
        for (int g = 0; g < 2; ++g)
            bf_[g] = *reinterpret_cast<bf16x8*>(
                &Bs[cur][(wn * 32 + 16 * g + c) * 40 + quad * 8]);
#pragma unroll
        for (int j = 0; j < 4; ++j)
#pragma unroll
            for (int g = 0; g < 2; ++g)
                acc[j][g] = __builtin_amdgcn_mfma_f32_16x16x32_bf16(
                    af[j], bf_[g], acc[j][g], 0, 0, 0);
    }
#pragma unroll
    for (int j = 0; j < 4; ++j)
#pragma unroll
        for (int r = 0; r < 4; ++r) {
            const int row = m0 + wm * 64 + 16 * j + quad * 4 + r;
            const int col = n0 + wn * 32 + c;
#pragma unroll
            for (int g = 0; g < 2; ++g)
                Out[(size_t)row * 512 + col + 16 * g] = acc[j][g][r];
        }
}

// ===========================================================================
// flash v15 (round-5/7/9 validated text, UNCHANGED): paired A/B q-blocks,
// T12 in-register P transform, XOR-swizzled unpadded K/V tiles. ~57us,
// absmax 0.015625. Un-paired variant failed correctness twice — do not
// re-attempt without a device-side debugging path.
// ===========================================================================
#define KSW(row, col) ((row) * 32 + ((col) ^ (((row) & 3) << 3)))
#define VSW(row, col) ((row) * 64 + ((col) ^ (((row) & 7) << 3)))

__global__ __launch_bounds__(512, 4) void flash_mfma(
    const u16* __restrict__ Q, const u16* __restrict__ K,
    const u16* __restrict__ V, u16* __restrict__ AO)
{
    __shared__ __align__(16) union {
        struct {
            u16 Kl[2][2][64 * 32];
            u16 Vt[2][2][64 * 64];
        } t;
        float mg[4][64][40];
    } sh;

    const int tid  = threadIdx.x;
    const int w    = tid >> 6;
    const int ws   = w & 3;
    const int wg   = w >> 2;
    const int lane = tid & 63;
    const int c    = lane & 15;
    const int quad = lane >> 4;
    const int h = blockIdx.y, b = blockIdx.z;

    const int qbA = blockIdx.x;
    const int qbB = 63 - qbA;
    const int q0A = qbA * 64, q0B = qbB * 64;

    const u16* Qb = Q + (size_t)b * SEQ * KDIM + h * DK;
    const u16* Kb = K + (size_t)b * SEQ * KDIM + h * DK;
    const u16* Vb = V + (size_t)b * SEQ * VDIM + h * DV;
    u16* AOb = AO + (size_t)b * SEQ * VDIM + h * DV;

    const bf16x8 qfA = *reinterpret_cast<const bf16x8*>(
        &Qb[(size_t)(q0A + ws * 16 + c) * KDIM + quad * 8]);
    const bf16x8 qfB = *reinterpret_cast<const bf16x8*>(
        &Qb[(size_t)(q0B + ws * 16 + c) * KDIM + quad * 8]);

    // constant all-ones A-frag: bf16 1.0 = 0x3F80 in every element
    const bf16x8 ones = {(short)0x3F80, (short)0x3F80, (short)0x3F80, (short)0x3F80,
                         (short)0x3F80, (short)0x3F80, (short)0x3F80, (short)0x3F80};

    f32x4 oA[4], oB[4];
#pragma unroll
    for (int g = 0; g < 4; ++g) {
        oA[g] = (f32x4){0.f, 0.f, 0.f, 0.f};
        oB[g] = (f32x4){0.f, 0.f, 0.f, 0.f};
    }
    f32x4 laccA = {0.f, 0.f, 0.f, 0.f}, laccB = {0.f, 0.f, 0.f, 0.f};

    const int t256 = tid & 255;
    const int krow = t256 >> 2, kc8 = (t256 & 3) * 8;
    const int vs0 = (t256 & 31) * 2, vd0 = (t256 >> 5) * 8;

    const int qrbase = ws * 16 + c;   // per-lane q row (within q-block)
    const int T = (qbB >> 1) + 1;

    uint4 kreg, vra, vrb;
    auto ldtile = [&](int kb) {
        const int k0 = kb * 64;
        kreg = *reinterpret_cast<const uint4*>(&Kb[(size_t)(k0 + krow) * KDIM + kc8]);
        vra  = *reinterpret_cast<const uint4*>(&Vb[(size_t)(k0 + vs0) * VDIM + vd0]);
        vrb  = *reinterpret_cast<const uint4*>(&Vb[(size_t)(k0 + vs0 + 1) * VDIM + vd0]);
    };
    auto stagetile = [&](int buf) {
        *reinterpret_cast<uint4*>(&sh.t.Kl[wg][buf][KSW(krow, kc8)]) = kreg;
        union { uint4 q; u16 s[8]; } ra, rb;
        ra.q = vra; rb.q = vrb;
#pragma unroll
        for (int i = 0; i < 8; ++i) {
            u32 packed = (u32)ra.s[i] | ((u32)rb.s[i] << 16);
            *reinterpret_cast<u32*>(&sh.t.Vt[wg][buf][VSW(vd0 + i, vs0)]) = packed;
        }
    };

    ldtile(wg);
    stagetile(0);
    ldtile(2 + wg);

    for (int it = 0; it < T; ++it) {
        const int kb = 2 * it + wg;
        const int k0 = kb * 64;
        const int cur = it & 1;
        __syncthreads();
        stagetile(cur ^ 1);
        {
            int kbn = 2 * (it + 2) + wg; if (kbn > 63) kbn = 63;
            ldtile(kbn);
        }
        const u16* Klc = sh.t.Kl[wg][cur];
        const u16* Vtc = sh.t.Vt[wg][cur];

        auto compute = [&](const bf16x8& qf, int q0, bool diag,
                           f32x4* o, f32x4& lacc) {
            // swapped QK^T: lane(c,quad) gets S[q=c][k=16g+quad*4+r]
            f32x4 s[4];
#pragma unroll
            for (int g = 0; g < 4; ++g) {
                const bf16x8 kf = *reinterpret_cast<const bf16x8*>(
                    &Klc[KSW(c + 16 * g, quad * 8)]);
                const f32x4 z = {0.f, 0.f, 0.f, 0.f};
                s[g] = __builtin_amdgcn_mfma_f32_16x16x32_bf16(kf, qf, z, 0, 0, 0);
            }
            if (diag) {
                const int qr = q0 + qrbase;
#pragma unroll
                for (int g = 0; g < 4; ++g) {
                    const int kc0 = k0 + 16 * g + quad * 4;
#pragma unroll
                    for (int r = 0; r < 4; ++r)
                        if (kc0 + r > qr) s[g][r] = -1e30f;
                }
            }
            // exp2 + pack: wk[g][j2] covers k = quad*4 + 16g + 2*j2 + {0,1}
            u32 wk[4][2];
#pragma unroll
            for (int g = 0; g < 4; ++g)
#pragma unroll
                for (int j2 = 0; j2 < 2; ++j2)
                    wk[g][j2] = cvtpk_bf16(
                        __builtin_amdgcn_exp2f(s[g][2 * j2]),
                        __builtin_amdgcn_exp2f(s[g][2 * j2 + 1]));
            // permutation network -> PV B-frags pb0 (k 0..31), pb1 (k 32..63)
            union { u32 wq[4]; bf16x8 v; } ub0, ub1;
#pragma unroll
            for (int j2 = 0; j2 < 2; ++j2) {
                {
                    auto t1 = __builtin_amdgcn_permlane32_swap(
                        wk[0][j2], wk[1][j2], false, false);
                    auto t2 = __builtin_amdgcn_permlane16_swap(
                        (u32)t1[0], (u32)t1[1], false, false);
                    ub0.wq[j2]     = (u32)t2[0];
                    ub0.wq[2 + j2] = (u32)t2[1];
                }
                {
                    auto t1 = __builtin_amdgcn_permlane32_swap(
                        wk[2][j2], wk[3][j2], false, false);
                    auto t2 = __builtin_amdgcn_permlane16_swap(
                        (u32)t1[0], (u32)t1[1], false, false);
                    ub1.wq[j2]     = (u32)t2[0];
                    ub1.wq[2 + j2] = (u32)t2[1];
                }
            }
            const bf16x8 pb0 = ub0.v, pb1 = ub1.v;
            // rowsum via matrix pipe: every reg of lacc holds l[q=c]
            lacc = __builtin_amdgcn_mfma_f32_16x16x32_bf16(ones, pb0, lacc, 0, 0, 0);
            lacc = __builtin_amdgcn_mfma_f32_16x16x32_bf16(ones, pb1, lacc, 0, 0, 0);
            // PV (transposed): o[g] holds O[q=c][dv=16g+quad*4+r]
#pragma unroll
            for (int g = 0; g < 4; ++g) {
                const bf16x8 v0 = *reinterpret_cast<const bf16x8*>(
                    &Vtc[VSW(c + 16 * g, quad * 8)]);
                const bf16x8 v1 = *reinterpret_cast<const bf16x8*>(
                    &Vtc[VSW(c + 16 * g, 32 + quad * 8)]);
                o[g] = __builtin_amdgcn_mfma_f32_16x16x32_bf16(v0, pb0, o[g], 0, 0, 0);
                o[g] = __builtin_amdgcn_mfma_f32_16x16x32_bf16(v1, pb1, o[g], 0, 0, 0);
            }
        };

        if (kb <= qbA) compute(qfA, q0A, kb == qbA, oA, laccA);
        if (kb <= qbB) compute(qfB, q0B, kb == qbB, oB, laccB);
    }

    __syncthreads();
    if (wg == 1) {
        float* m = sh.mg[ws][lane];
#pragma unroll
        for (int g = 0; g < 4; ++g)
#pragma unroll
            for (int r = 0; r < 4; ++r) {
                m[g * 4 + r]      = oA[g][r];
                m[16 + g * 4 + r] = oB[g][r];
            }
        m[32] = laccA[0];
        m[33] = laccB[0];
    }
    __syncthreads();
    if (wg == 0) {
        const float* m = sh.mg[ws][lane];
#pragma unroll
        for (int g = 0; g < 4; ++g)
#pragma unroll
            for (int r = 0; r < 4; ++r) {
                oA[g][r] += m[g * 4 + r];
                oB[g][r] += m[16 + g * 4 + r];
            }
        const float invA = 1.f / (laccA[0] + m[32]);
        const float invB = 1.f / (laccB[0] + m[33]);
        const int rowA = q0A + qrbase;
        const int rowB = q0B + qrbase;
#pragma unroll
        for (int g = 0; g < 4; ++g) {
            ushort4 a4, b4;
            a4.x = f2bf(oA[g][0] * invA); a4.y = f2bf(oA[g][1] * invA);
            a4.z = f2bf(oA[g][2] * invA); a4.w = f2bf(oA[g][3] * invA);
            b4.x = f2bf(oB[g][0] * invB); b4.y = f2bf(oB[g][1] * invB);
            b4.z = f2bf(oB[g][2] * invB); b4.w = f2bf(oB[g][3] * invB);
            *reinterpret_cast<ushort4*>(
                &AOb[(size_t)rowA * VDIM + 16 * g + quad * 4]) = a4;
            *reinterpret_cast<ushort4*>(
                &AOb[(size_t)rowB * VDIM + 16 * g + quad * 4]) = b4;
        }
    }
}

// ===========================================================================
// FALLBACK PATH (ws too small): round-10 projection kernels
// ===========================================================================
__global__ __launch_bounds__(256) void qkv_proj(
    const float* __restrict__ X,
    const float* __restrict__ Wq, const float* __restrict__ Wk,
    const float* __restrict__ Wv,
    u16* __restrict__ Qh, u16* __restrict__ Kh, u16* __restrict__ Vh)
{
    __shared__ __align__(16) u16 Xs[2][64 * 40];
    __shared__ __align__(16) u16 Wsm[2][64 * 40];
    const int tid = threadIdx.x;
    const int w = tid >> 6, lane = tid & 63;
    const int c = lane & 15, quad = lane >> 4;
    const int s0 = blockIdx.x * 64, b = blockIdx.z;
    const int ny = blockIdx.y;

    const float* Wt; u16* Y; int N, n0; float scale;
    if (ny < 4)       { Wt = Wq; Y = Qh; N = KDIM; n0 = ny * 64;       scale = QSCALE; }
    else if (ny < 8)  { Wt = Wk; Y = Kh; N = KDIM; n0 = (ny - 4) * 64; scale = 1.0f; }
    else              { Wt = Wv; Y = Vh; N = VDIM; n0 = (ny - 8) * 64; scale = 1.0f; }

    const float* Xb = X + (size_t)b * CH * SEQ;
    const int cp = tid >> 4;
    const int s4 = (tid & 15) * 4;

    f32x4 acc[4];
#pragma unroll
    for (int g = 0; g < 4; ++g) acc[g] = (f32x4){0.f, 0.f, 0.f, 0.f};

    auto ldx = [&](int c0, float4& a, float4& bb) {
        a  = *reinterpret_cast<const float4*>(&Xb[(size_t)(c0 + 2 * cp) * SEQ + s0 + s4]);
        bb = *reinterpret_cast<const float4*>(&Xb[(size_t)(c0 + 2 * cp + 1) * SEQ + s0 + s4]);
    };
    auto ldwf = [&](int c0, float4& a, float4& bb) {
        a  = *reinterpret_cast<const float4*>(&Wt[(size_t)(c0 + 2 * cp) * N + n0 + s4]);
        bb = *reinterpret_cast<const float4*>(&Wt[(size_t)(c0 + 2 * cp + 1) * N + n0 + s4]);
    };
    auto stage = [&](int buf, const float4& xa, const float4& xb,
                     const float4& wa, const float4& wb) {
        const float a[4] = {xa.x, xa.y, xa.z, xa.w};
        const float bb[4] = {xb.x, xb.y, xb.z, xb.w};
        const float aw[4] = {wa.x, wa.y, wa.z, wa.w};
        const float bw[4] = {wb.x, wb.y, wb.z, wb.w};
#pragma unroll
        for (int i = 0; i < 4; ++i) {
            *reinterpret_cast<u32*>(&Xs[buf][(s4 + i) * 40 + 2 * cp]) = pack2f(a[i], bb[i]);
            *reinterpret_cast<u32*>(&Wsm[buf][(s4 + i) * 40 + 2 * cp]) = pack2f(aw[i], bw[i]);
        }
    };

    float4 xa, xb, wa, wb;
    ldx(0, xa, xb); ldwf(0, wa, wb);
    stage(0, xa, xb, wa, wb);
    ldx(32, xa, xb); ldwf(32, wa, wb);

    for (int i = 0; i < 16; ++i) {
        const int cur = i & 1;
        __syncthreads();
        stage(cur ^ 1, xa, xb, wa, wb);
        const int c0n = (i + 2 < 16) ? (i + 2) * 32 : 15 * 32;
        ldx(c0n, xa, xb); ldwf(c0n, wa, wb);
        const bf16x8 af = *reinterpret_cast<bf16x8*>(&Xs[cur][(w * 16 + c) * 40 + quad * 8]);
#pragma unroll
        for (int g = 0; g < 4; ++g) {
            bf16x8 bf_ = *reinterpret_cast<bf16x8*>(&Wsm[cur][(c + 16 * g) * 40 + quad * 8]);
            acc[g] = __builtin_amdgcn_mfma_f32_16x16x32_bf16(af, bf_, acc[g], 0, 0, 0);
        }
    }
    u16* Yb = Y + (size_t)b * SEQ * N;
#pragma unroll
    for (int r = 0; r < 4; ++r) {
        const int row = s0 + w * 16 + quad * 4 + r;
#pragma unroll
        for (int g = 0; g < 4; ++g)
            Yb[(size_t)row * N + n0 + c + 16 * g] = f2bf(acc[g][r] * scale);
    }
}

__global__ __launch_bounds__(256) void oproj_mfma(
    const u16* __restrict__ A, const float* __restrict__ Wo,
    float* __restrict__ Out)
{
    __shared__ __align__(16) u16 Ws[2][64 * 40];
    const int tid = threadIdx.x;
    const int w = tid >> 6, lane = tid & 63;
    const int c = lane & 15, quad = lane >> 4;
    const int m0 = blockIdx.x * 64, n0 = blockIdx.y * 64;
    const int kp = tid >> 4;
    const int n4 = (tid & 15) * 4;
    const u16* Arow = &A[(size_t)(m0 + w * 16 + c) * 512];

    f32x4 acc[4];
#pragma unroll
    for (int g = 0; g < 4; ++g) acc[g] = (f32x4){0.f, 0.f, 0.f, 0.f};

    auto ldwf = [&](int k0, float4& a, float4& bb) {
        a  = *reinterpret_cast<const float4*>(&Wo[(size_t)(k0 + 2 * kp) * 512 + n0 + n4]);
        bb = *reinterpret_cast<const float4*>(&Wo[(size_t)(k0 + 2 * kp + 1) * 512 + n0 + n4]);
    };
    auto stage = [&](int buf, const float4& wa, const float4& wb) {
        const float a[4] = {wa.x, wa.y, wa.z, wa.w};
        const float bb[4] = {wb.x, wb.y, wb.z, wb.w};
#pragma unroll
        for (int i = 0; i < 4; ++i)
            *reinterpret_cast<u32*>(&Ws[buf][(n4 + i) * 40 + 2 * kp]) = pack2f(a[i], bb[i]);
    };

    float4 wa, wb;
    ldwf(0, wa, wb);
    stage(0, wa, wb);
    ldwf(32, wa, wb);
    bf16x8 afc = *reinterpret_cast<const bf16x8*>(&Arow[quad * 8]);

    for (int i = 0; i < 16; ++i) {
        const int cur = i & 1;
        __syncthreads();
        stage(cur ^ 1, wa, wb);
        const int k0n = (i + 2 < 16) ? (i + 2) * 32 : 15 * 32;
        ldwf(k0n, wa, wb);
        const int k0a = (i + 1 < 16) ? (i + 1) * 32 : 15 * 32;
        const bf16x8 afn = *reinterpret_cast<const bf16x8*>(&Arow[k0a + quad * 8]);
#pragma unroll
        for (int g = 0; g < 4; ++g) {
            bf16x8 bf_ = *reinterpret_cast<bf16x8*>(&Ws[cur][(c + 16 * g) * 40 + quad * 8]);
            acc[g] = __builtin_amdgcn_mfma_f32_16x16x32_bf16(afc, bf_, acc[g], 0, 0, 0);
        }
        afc = afn;
    }
#pragma unroll
    for (int r = 0; r < 4; ++r) {
        const int row = m0 + w * 16 + quad * 4 + r;
#pragma unroll
        for (int g = 0; g < 4; ++g)
            Out[(size_t)row * 512 + n0 + c + 16 * g] = acc[g][r];
    }
}

extern "C" void kernel_launch(void* const* d_in, const int* in_sizes, int n_in,
                              void* d_out, int out_size, void* d_ws, size_t ws_size,
                              hipStream_t stream) {
    const float* X  = (const float*)d_in[0];
    const float* Wq = (const float*)d_in[1];
    const float* Wk = (const float*)d_in[2];
    const float* Wv = (const float*)d_in[3];
    const float* Wo = (const float*)d_in[4];
    float* out = (float*)d_out;

    const size_t qk = (size_t)BATCH * SEQ * KDIM;
    const size_t vs = (size_t)BATCH * SEQ * VDIM;
    u16* Qh  = (u16*)d_ws;        // 4 MB
    u16* Kh  = Qh + qk;           // 4 MB
    u16* Vh  = Kh + qk;           // 8 MB
    u16* XA  = Vh + vs;           // 8 MB: AO after flash (Xb16 slot retired)
    u16* Wall = XA + vs;          // 1 MB
    u16* WoT  = Wall + 1024 * 512;// 0.5 MB
    const size_t need_fast = (size_t)(WoT + 512 * 512 - (u16*)d_ws) * sizeof(u16);

    if (ws_size >= need_fast) {
        prep<<<dim3(192), 256, 0, stream>>>(Wq, Wk, Wv, Wo, Wall, WoT);
        qkvX<<<dim3((BATCH * SEQ) / 128, 8), 256, 0, stream>>>(X, Wall, Qh, Kh, Vh);
        flash_mfma<<<dim3(32, NHEADS, BATCH), 512, 0, stream>>>(Qh, Kh, Vh, XA);
        oproj3<<<dim3((BATCH * SEQ) / 128, 8), 256, 0, stream>>>(XA, WoT, out);
    } else {
        u16* AOh = XA;
        qkv_proj<<<dim3(SEQ / 64, 16, BATCH), 256, 0, stream>>>(
            X, Wq, Wk, Wv, Qh, Kh, Vh);
        flash_mfma<<<dim3(32, NHEADS, BATCH), 512, 0, stream>>>(Qh, Kh, Vh, AOh);
        oproj_mfma<<<dim3((BATCH * SEQ) / 64, VDIM / 64), 256, 0, stream>>>(AOh, Wo, out);
    }
}